// Round 12
// baseline (372.820 us; speedup 1.0000x reference)
//
#include <hip/hip_runtime.h>
#include <hip/hip_bf16.h>
#include <stdint.h>

#define B_ 4
#define S_ 2048
#define D_ 1024
#define M_ 4

typedef __bf16 bf16;
typedef _Float16 f16;
typedef unsigned char u8;
typedef __bf16 bf16x8 __attribute__((ext_vector_type(8)));
typedef _Float16 f16x8 __attribute__((ext_vector_type(8)));
typedef float f32x4 __attribute__((ext_vector_type(4)));

__device__ __forceinline__ void async_copy16(const void* g, void* l) {
  __builtin_amdgcn_global_load_lds(
      (const __attribute__((address_space(1))) void*)g,
      (__attribute__((address_space(3))) void*)l, 16, 0, 0);
}

// Fused prep, block ranges:
//   [0,4096)      : x fp32 -> bf16
//   [4096,5120)   : 4x W [1024,1024] fp32 -> WT bf16 (256 blocks each)
//   [5120,7168)   : pack 4 masks -> bitfield bytes
__global__ __launch_bounds__(256) void prep(
    const float* __restrict__ x, const float* __restrict__ w0,
    const float* __restrict__ w1, const float* __restrict__ w2,
    const float* __restrict__ w3, const int* __restrict__ masks,
    bf16* __restrict__ xc, bf16* __restrict__ WT, u8* __restrict__ pk) {
  __shared__ bf16 t[64][65];
  const int blk = blockIdx.x;
  const int tid = threadIdx.x;
  const long SS = (long)S_ * S_;

  if (blk < 4096) {  // x -> bf16
    const long i = (long)blk * 2048 + tid * 8;
    const float4 a = *(const float4*)(x + i);
    const float4 b = *(const float4*)(x + i + 4);
    bf16x8 o;
    o[0] = (bf16)a.x; o[1] = (bf16)a.y; o[2] = (bf16)a.z; o[3] = (bf16)a.w;
    o[4] = (bf16)b.x; o[5] = (bf16)b.y; o[6] = (bf16)b.z; o[7] = (bf16)b.w;
    *(bf16x8*)(xc + i) = o;
  } else if (blk < 5120) {  // weight transpose -> bf16
    const int local = blk - 4096;
    const int z = local >> 8;
    const int rem = local & 255;
    const int r0 = (rem >> 4) * 64;
    const int c0 = (rem & 15) * 64;
    const int tx = tid & 63;
    const int ty = tid >> 6;
    const float* in = (z == 0) ? w0 : (z == 1) ? w1 : (z == 2) ? w2 : w3;
    bf16* out = WT + (long)z * D_ * D_;
    for (int i = ty; i < 64; i += 4)
      t[i][tx] = (bf16)in[(long)(r0 + i) * D_ + c0 + tx];
    __syncthreads();
    for (int i = ty; i < 64; i += 4)
      out[(long)(c0 + i) * D_ + r0 + tx] = t[tx][i];
  } else {  // pack masks
    const long e = (long)(blk - 5120) * 2048 + tid * 8;
    unsigned long long wv = 0;
#pragma unroll
    for (int m = 0; m < M_; ++m) {
      const int4 a = *(const int4*)(masks + m * SS + e);
      const int4 b = *(const int4*)(masks + m * SS + e + 4);
      const int v[8] = {a.x, a.y, a.z, a.w, b.x, b.y, b.z, b.w};
#pragma unroll
      for (int j = 0; j < 8; ++j)
        wv |= (unsigned long long)(v[j] != 0 ? 1u : 0u) << (8 * j + m);
    }
    *(unsigned long long*)(pk + e) = wv;
  }
}

// batched bf16 [rows,cols] -> [cols,rows] transpose (z = batch)
__global__ __launch_bounds__(256) void transposeB(
    const bf16* __restrict__ in, bf16* __restrict__ out,
    int rows, int cols, long ib, long ob) {
  __shared__ bf16 t[64][65];
  in += (long)blockIdx.z * ib;
  out += (long)blockIdx.z * ob;
  const int r0 = blockIdx.y * 64;
  const int c0 = blockIdx.x * 64;
  const int tx = threadIdx.x & 63;
  const int ty = threadIdx.x >> 6;
#pragma unroll
  for (int i = ty; i < 64; i += 4) t[i][tx] = in[(long)(r0 + i) * cols + c0 + tx];
  __syncthreads();
#pragma unroll
  for (int i = ty; i < 64; i += 4) out[(long)(c0 + i) * rows + r0 + tx] = t[tx][i];
}

#define MODE_PLAIN 0
#define MODE_EXP 1   // C = exp(alpha*acc), f16 out; B z-batched by row0>>11
#define MODE_QKV 2   // N=3072 grouped epilogue: Q | K | V
#define MODE_PV 3    // B z-batched by row0>>11

// ---------- 256x128 3-slot rotating counted-vmcnt GEMM, 8 waves ----------
// r8-verified structure (350.8 us total). 512 threads = 8 waves (4M x 2N),
// per-wave 64x64 (acc 4x4). LDS 72 KiB -> 2 blocks/CU.
// Session laws: (r10) wave/SIMD density >= 4 beats LDS-bytes/FLOP (4-wave fat
// tile collapsed 6x); (r11) BN=64 worsens bytes/FLOP 1.5x, cancelling 2/CU gain.
// r12 change: VECTORIZED EPILOGUE. The old epilogue issued 64 scalar 2B/4B
// stores per thread (isolated 32B segments, instruction-rate bound) across all
// four GEMMs (~25M scalar stores/iter) — the only candidate for the ~140 us
// gap between memory-floor budget and measured total. New epilogue: per-wave
// LDS transpose ([16][68] f32, pad-68 keeps read-back 2-way/free) then 16B
// coalesced stores (128B contiguous per 4 lanes), 8-32x fewer store instrs.
template <typename OutT, int MODE>
__global__ __launch_bounds__(512) void gemmA(
    const bf16* __restrict__ A, int lda,
    const bf16* __restrict__ Bt, long bzs, int ldb,
    OutT* __restrict__ C, int ldc,
    const float* __restrict__ bias0, const float* __restrict__ bias1,
    const float* __restrict__ bias2, float alpha, int K) {
  __shared__ __align__(16) bf16 As[3][256 * 32];
  __shared__ __align__(16) bf16 Bs[3][128 * 32];
  const int tid = threadIdx.x;
  const int lane = tid & 63;
  const int w = tid >> 6;
  const int wm = w & 3;
  const int wn = w >> 2;
  const int quad = lane >> 4;
  const int l15 = lane & 15;
  const int fse = (quad ^ ((l15 >> 1) & 3)) << 3;

  const int gx = gridDim.x;
  const int pid = blockIdx.y * gx + blockIdx.x;
  const int gsz = 8 * gx;
  const int bym = (pid / gsz) * 8 + (pid % 8);
  const int bxm = (pid % gsz) / 8;
  const int row0 = bym * 256;
  const int col0 = bxm * 128;

  const bf16* Arow = A + (long)row0 * lda;
  const bf16* Bcol;
  int grp = 0;
  if (MODE == MODE_QKV) {
    grp = col0 >> 10;
    Bcol = Bt + (long)grp * ((long)D_ * D_) + (long)(col0 & (D_ - 1)) * ldb;
  } else if (MODE == MODE_PV || MODE == MODE_EXP) {
    Bcol = Bt + (long)(row0 >> 11) * bzs + (long)col0 * ldb;
  } else {
    Bcol = Bt + (long)col0 * ldb;
  }

  const int sr = tid >> 2;
  const int sc = ((tid & 3) ^ ((tid >> 3) & 3)) << 3;
  const bf16* gA = Arow + (long)sr * lda + sc;
  const bf16* gB = Bcol + (long)sr * ldb + sc;
  const int dstoff = (tid >> 6) << 9;
  const long a128 = (long)128 * lda;

#define STAGE(h, s)                                                    \
  {                                                                    \
    const int kc_ = (h) * 32;                                          \
    bf16* da_ = &As[0][0] + (s) * (256 * 32) + dstoff;                 \
    bf16* db_ = &Bs[0][0] + (s) * (128 * 32) + dstoff;                 \
    async_copy16(gA + kc_, da_);                                       \
    async_copy16(gA + kc_ + a128, da_ + 4096);                         \
    async_copy16(gB + kc_, db_);                                       \
  }

#define READF(Ra, Rb, s)                                                   \
  {                                                                        \
    const bf16* pa_ = &As[0][0] + (s) * (256 * 32);                        \
    const bf16* pb_ = &Bs[0][0] + (s) * (128 * 32);                        \
    _Pragma("unroll") for (int j = 0; j < 4; ++j) {                        \
      Ra[j] = *(const bf16x8*)&pa_[(wm * 64 + j * 16 + l15) * 32 + fse];   \
      Rb[j] = *(const bf16x8*)&pb_[(wn * 64 + j * 16 + l15) * 32 + fse];   \
    }                                                                      \
  }

#define MM(Ra, Rb)                                                         \
  __builtin_amdgcn_s_setprio(1);                                           \
  _Pragma("unroll") for (int mi = 0; mi < 4; ++mi)                         \
      _Pragma("unroll") for (int ni = 0; ni < 4; ++ni) acc[mi][ni] =       \
          __builtin_amdgcn_mfma_f32_16x16x32_bf16(Ra[mi], Rb[ni],          \
                                                  acc[mi][ni], 0, 0, 0);   \
  __builtin_amdgcn_s_setprio(0);

  f32x4 acc[4][4];
#pragma unroll
  for (int i = 0; i < 4; ++i)
#pragma unroll
    for (int j = 0; j < 4; ++j) acc[i][j] = (f32x4){0.f, 0.f, 0.f, 0.f};

  const int nh = (K >> 6) << 1;

  STAGE(0, 0);
  STAGE(1, 1);
  asm volatile("s_waitcnt vmcnt(3)" ::: "memory");
  __builtin_amdgcn_s_barrier();
  __builtin_amdgcn_sched_barrier(0);

  int s0 = 0;
  for (int h = 0; h < nh; ++h) {
    bf16x8 af[4], bf[4];
    READF(af, bf, s0);
    if (h + 2 < nh) {
      const int s2 = (s0 >= 1) ? (s0 - 1) : 2;
      STAGE(h + 2, s2);
    }
    MM(af, bf);
    if (h + 2 < nh)
      asm volatile("s_waitcnt vmcnt(3)" ::: "memory");
    else if (h + 1 < nh)
      asm volatile("s_waitcnt vmcnt(0)" ::: "memory");
    if (h + 1 < nh) {
      __builtin_amdgcn_s_barrier();
      __builtin_amdgcn_sched_barrier(0);
    }
    s0 = (s0 == 2) ? 0 : (s0 + 1);
  }

#undef STAGE
#undef READF
#undef MM

  // ---- vectorized epilogue: per-wave LDS transpose -> coalesced 16B stores ----
  // All waves must be done reading As/Bs before we reuse As as scratch.
  __syncthreads();

  const float* bias = (MODE == MODE_QKV)
                          ? (grp == 0 ? bias0 : grp == 1 ? bias1 : bias2)
                          : bias0;
  const long NX = (long)B_ * S_ * D_;
  OutT* Cb = (MODE == MODE_QKV) ? C + (long)grp * NX : C;

  // per-wave scratch: [16 rows][68 f32] = 4352 B; 8 waves = 34.8 KB <= As (48 KB)
  float* sm = (float*)&As[0][0] + w * (16 * 68);
  const int erow = lane >> 2;         // 0..15 local row
  const int ecc = (lane & 3) << 4;    // 0,16,32,48 local col chunk

#pragma unroll
  for (int mi = 0; mi < 4; ++mi) {
    // scatter acc (col=l15, rows quad*4+r) into [row][col] layout (2-way banks, free)
#pragma unroll
    for (int ni = 0; ni < 4; ++ni)
#pragma unroll
      for (int r = 0; r < 4; ++r)
        sm[(quad * 4 + r) * 68 + ni * 16 + l15] = acc[mi][ni][r];
    asm volatile("s_waitcnt lgkmcnt(0)" ::: "memory");
    __builtin_amdgcn_sched_barrier(0);

    // gather: lane owns 16 consecutive cols of one row (16B-aligned, 2-way banks)
    float4 v0 = *(const float4*)&sm[erow * 68 + ecc + 0];
    float4 v1 = *(const float4*)&sm[erow * 68 + ecc + 4];
    float4 v2 = *(const float4*)&sm[erow * 68 + ecc + 8];
    float4 v3 = *(const float4*)&sm[erow * 68 + ecc + 12];
    asm volatile("s_waitcnt lgkmcnt(0)" ::: "memory");
    __builtin_amdgcn_sched_barrier(0);

    const int row = row0 + wm * 64 + mi * 16 + erow;
    const int colb = col0 + wn * 64 + ecc;
    const int cb2 = (MODE == MODE_QKV) ? (colb & (D_ - 1)) : colb;
    const float* bp = bias ? &bias[cb2] : nullptr;
    float vf[16] = {v0.x, v0.y, v0.z, v0.w, v1.x, v1.y, v1.z, v1.w,
                    v2.x, v2.y, v2.z, v2.w, v3.x, v3.y, v3.z, v3.w};
#pragma unroll
    for (int j = 0; j < 16; ++j) {
      float val = vf[j] * alpha + (bp ? bp[j] : 0.0f);
      if (MODE == MODE_EXP) val = __expf(val);
      vf[j] = val;
    }
    OutT* dst = (MODE == MODE_QKV) ? &Cb[(long)row * D_ + cb2]
                                   : &Cb[(long)row * ldc + colb];
    if constexpr (sizeof(OutT) == 2) {
      typedef OutT OutT8 __attribute__((ext_vector_type(8)));
      OutT8 o0, o1;
#pragma unroll
      for (int j = 0; j < 8; ++j) { o0[j] = (OutT)vf[j]; o1[j] = (OutT)vf[j + 8]; }
      *(OutT8*)(dst) = o0;
      *(OutT8*)(dst + 8) = o1;
    } else {
      float4 q0 = {vf[0], vf[1], vf[2], vf[3]};
      float4 q1 = {vf[4], vf[5], vf[6], vf[7]};
      float4 q2 = {vf[8], vf[9], vf[10], vf[11]};
      float4 q3 = {vf[12], vf[13], vf[14], vf[15]};
      *(float4*)(dst) = q0;
      *(float4*)(dst + 4) = q1;
      *(float4*)(dst + 8) = q2;
      *(float4*)(dst + 12) = q3;
    }
  }
}

// grid (S, B): P[b,q,:] = E[b,q,:] * sum_m bit_m(q,:) / rowsum_m / M, bf16.
__global__ __launch_bounds__(256) void softmax_combine(
    const f16* __restrict__ E, const u8* __restrict__ pk, bf16* __restrict__ P) {
  const int q = blockIdx.x;
  const int b = blockIdx.y;
  const int tid = threadIdx.x;
  const int lane = tid & 63;
  const int wv = tid >> 6;
  __shared__ float4 red[4];

  float e[8];
  {
    const f16x8 h = *(const f16x8*)(E + ((long)b * S_ + q) * S_ + tid * 8);
#pragma unroll
    for (int j = 0; j < 8; ++j) e[j] = (float)h[j];
  }
  const unsigned long long mb =
      *(const unsigned long long*)(pk + (long)q * S_ + tid * 8);

  float4 s = {0.f, 0.f, 0.f, 0.f};
#pragma unroll
  for (int j = 0; j < 8; ++j) {
    const unsigned bits = (unsigned)(mb >> (8 * j)) & 0xF;
    const float ev = e[j];
    if (bits & 1) s.x += ev;
    if (bits & 2) s.y += ev;
    if (bits & 4) s.z += ev;
    if (bits & 8) s.w += ev;
  }
#pragma unroll
  for (int o = 32; o > 0; o >>= 1) {
    s.x += __shfl_xor(s.x, o, 64);
    s.y += __shfl_xor(s.y, o, 64);
    s.z += __shfl_xor(s.z, o, 64);
    s.w += __shfl_xor(s.w, o, 64);
  }
  if (lane == 0) red[wv] = s;
  __syncthreads();
  const float4 t0 = red[0], t1 = red[1], t2 = red[2], t3 = red[3];
  const float r0 = 0.25f / (t0.x + t1.x + t2.x + t3.x);
  const float r1 = 0.25f / (t0.y + t1.y + t2.y + t3.y);
  const float r2 = 0.25f / (t0.z + t1.z + t2.z + t3.z);
  const float r3 = 0.25f / (t0.w + t1.w + t2.w + t3.w);

  bf16x8 o;
#pragma unroll
  for (int j = 0; j < 8; ++j) {
    const unsigned bits = (unsigned)(mb >> (8 * j)) & 0xF;
    const float wgt = ((bits & 1) ? r0 : 0.f) + ((bits & 2) ? r1 : 0.f) +
                      ((bits & 4) ? r2 : 0.f) + ((bits & 8) ? r3 : 0.f);
    o[j] = (bf16)(e[j] * wgt);
  }
  *(bf16x8*)(P + ((long)b * S_ + q) * S_ + tid * 8) = o;
}

extern "C" void kernel_launch(void* const* d_in, const int* in_sizes, int n_in,
                              void* d_out, int out_size, void* d_ws, size_t ws_size,
                              hipStream_t stream) {
  const float* x = (const float*)d_in[0];
  const int* masks = (const int*)d_in[1];
  const float* bq = (const float*)d_in[3];
  const float* bk = (const float*)d_in[5];
  const float* bv = (const float*)d_in[7];
  const float* bo = (const float*)d_in[9];
  float* out = (float*)d_out;

  const long DD = (long)D_ * D_;
  const long SD = (long)S_ * D_;
  const long NX = (long)B_ * SD;
  const long SS = (long)S_ * S_;

  // ws: xc 16M | WT 8M | pk 4M | Q/K/V 48M | VT 16M | P 32M | E 32M = 156 MiB
  bf16* xc = (bf16*)d_ws;
  bf16* WqT = xc + NX;  // WkT, WvT, WoT contiguous after
  bf16* WoT = WqT + 3 * DD;
  u8* pk = (u8*)(WoT + DD);    // [S][S] mask bitfield
  bf16* Q = (bf16*)(pk + SS);  // K = Q+NX, V = K+NX (QKV epilogue relies on it)
  bf16* K = Q + NX;
  bf16* V = K + NX;
  bf16* VT = V + NX;
  bf16* P = VT + NX;                   // [B][S][S] bf16
  f16* E = (f16*)(P + (long)B_ * SS);  // [B][S][S] f16
  bf16* attn = Q;                      // attn overwrites dead Q

  dim3 blk(256);
  dim3 blk512(512);

  // fused prep: x->bf16, 4 weight transposes, mask pack (one launch)
  prep<<<dim3(7168), blk, 0, stream>>>(
      x, (const float*)d_in[2], (const float*)d_in[4], (const float*)d_in[6],
      (const float*)d_in[8], masks, xc, WqT, pk);

  // fused Q|K|V projection: [8192,1024] x [1024,3072] (r8 grids)
  gemmA<bf16, MODE_QKV><<<dim3(24, 32), blk512, 0, stream>>>(
      xc, D_, WqT, 0, D_, Q, D_, bq, bk, bv, 1.0f, D_);

  // VT[b][d][s] = V[b][s][d]
  transposeB<<<dim3(16, 32, B_), blk, 0, stream>>>(V, VT, S_, D_, SD, SD);

  // E = exp(Q K^T / 32) : flat [8192,1024] x K[z][2048,1024], z = row>>11
  gemmA<f16, MODE_EXP><<<dim3(16, 32), blk512, 0, stream>>>(
      Q, D_, K, SD, D_, E, S_, nullptr, nullptr, nullptr, 1.0f / 32.0f, D_);

  // P = E * sum_m mask_m / rowsum_m / M
  softmax_combine<<<dim3(S_, B_), blk, 0, stream>>>(E, pk, P);

  // attn = P @ V : flat [8192,2048] x VT[z][1024,2048], K=2048 (r8 config)
  gemmA<bf16, MODE_PV><<<dim3(8, 32), blk512, 0, stream>>>(
      P, S_, VT, SD, S_, attn, D_, nullptr, nullptr, nullptr, 1.0f, S_);

  // out = attn @ Wo + bo : fp32 epilogue straight to d_out (r8 config)
  gemmA<float, MODE_PLAIN><<<dim3(8, 32), blk512, 0, stream>>>(
      attn, D_, WoT, 0, D_, out, D_, bo, nullptr, nullptr, 1.0f, D_);
}

// Round 13
// 346.000 us; speedup vs baseline: 1.0775x; 1.0775x over previous
//
#include <hip/hip_runtime.h>
#include <hip/hip_bf16.h>
#include <stdint.h>

#define B_ 4
#define S_ 2048
#define D_ 1024
#define M_ 4

typedef __bf16 bf16;
typedef _Float16 f16;
typedef unsigned char u8;
typedef __bf16 bf16x8 __attribute__((ext_vector_type(8)));
typedef _Float16 f16x8 __attribute__((ext_vector_type(8)));
typedef float f32x4 __attribute__((ext_vector_type(4)));

__device__ __forceinline__ void async_copy16(const void* g, void* l) {
  __builtin_amdgcn_global_load_lds(
      (const __attribute__((address_space(1))) void*)g,
      (__attribute__((address_space(3))) void*)l, 16, 0, 0);
}

// Fused prep, block ranges:
//   [0,4096)      : x fp32 -> bf16
//   [4096,5120)   : 4x W [1024,1024] fp32 -> WT bf16 (256 blocks each)
//   [5120,7168)   : pack 4 masks -> bitfield bytes
__global__ __launch_bounds__(256) void prep(
    const float* __restrict__ x, const float* __restrict__ w0,
    const float* __restrict__ w1, const float* __restrict__ w2,
    const float* __restrict__ w3, const int* __restrict__ masks,
    bf16* __restrict__ xc, bf16* __restrict__ WT, u8* __restrict__ pk) {
  __shared__ bf16 t[64][65];
  const int blk = blockIdx.x;
  const int tid = threadIdx.x;
  const long SS = (long)S_ * S_;

  if (blk < 4096) {  // x -> bf16
    const long i = (long)blk * 2048 + tid * 8;
    const float4 a = *(const float4*)(x + i);
    const float4 b = *(const float4*)(x + i + 4);
    bf16x8 o;
    o[0] = (bf16)a.x; o[1] = (bf16)a.y; o[2] = (bf16)a.z; o[3] = (bf16)a.w;
    o[4] = (bf16)b.x; o[5] = (bf16)b.y; o[6] = (bf16)b.z; o[7] = (bf16)b.w;
    *(bf16x8*)(xc + i) = o;
  } else if (blk < 5120) {  // weight transpose -> bf16
    const int local = blk - 4096;
    const int z = local >> 8;
    const int rem = local & 255;
    const int r0 = (rem >> 4) * 64;
    const int c0 = (rem & 15) * 64;
    const int tx = tid & 63;
    const int ty = tid >> 6;
    const float* in = (z == 0) ? w0 : (z == 1) ? w1 : (z == 2) ? w2 : w3;
    bf16* out = WT + (long)z * D_ * D_;
    for (int i = ty; i < 64; i += 4)
      t[i][tx] = (bf16)in[(long)(r0 + i) * D_ + c0 + tx];
    __syncthreads();
    for (int i = ty; i < 64; i += 4)
      out[(long)(c0 + i) * D_ + r0 + tx] = t[tx][i];
  } else {  // pack masks
    const long e = (long)(blk - 5120) * 2048 + tid * 8;
    unsigned long long wv = 0;
#pragma unroll
    for (int m = 0; m < M_; ++m) {
      const int4 a = *(const int4*)(masks + m * SS + e);
      const int4 b = *(const int4*)(masks + m * SS + e + 4);
      const int v[8] = {a.x, a.y, a.z, a.w, b.x, b.y, b.z, b.w};
#pragma unroll
      for (int j = 0; j < 8; ++j)
        wv |= (unsigned long long)(v[j] != 0 ? 1u : 0u) << (8 * j + m);
    }
    *(unsigned long long*)(pk + e) = wv;
  }
}

// batched bf16 [rows,cols] -> [cols,rows] transpose (z = batch)
__global__ __launch_bounds__(256) void transposeB(
    const bf16* __restrict__ in, bf16* __restrict__ out,
    int rows, int cols, long ib, long ob) {
  __shared__ bf16 t[64][65];
  in += (long)blockIdx.z * ib;
  out += (long)blockIdx.z * ob;
  const int r0 = blockIdx.y * 64;
  const int c0 = blockIdx.x * 64;
  const int tx = threadIdx.x & 63;
  const int ty = threadIdx.x >> 6;
#pragma unroll
  for (int i = ty; i < 64; i += 4) t[i][tx] = in[(long)(r0 + i) * cols + c0 + tx];
  __syncthreads();
#pragma unroll
  for (int i = ty; i < 64; i += 4) out[(long)(c0 + i) * rows + r0 + tx] = t[tx][i];
}

#define MODE_PLAIN 0
#define MODE_EXP 1   // C = exp(alpha*acc), f16 out; B z-batched by row0>>11
#define MODE_QKV 2   // N=3072 grouped epilogue: Q | K | V
#define MODE_PV 3    // B z-batched by row0>>11

// ---------- 256x128 3-slot rotating counted-vmcnt GEMM, 8 waves ----------
// r8-verified structure (350.8 us total best; r13 = byte-exact revert to r8
// after r10/r11/r12 refutations). 512 threads = 8 waves (4M x 2N), per-wave
// 64x64 (acc 4x4). LDS 72 KiB -> 2 blocks/CU (16 waves/CU = 4 waves/SIMD).
// Session laws (all measured):
//  (r10) wave/SIMD density >= 4 beats LDS-bytes/FLOP — 4-wave fat tile = 6x collapse.
//  (r11) per-wave 64x32 tiles (BN=64) worsen bytes/FLOP 1.5x, cancelling 2/CU gain.
//  (r12) scalar epilogue stores are already HW-coalesced; LDS-transpose epilogue
//        costs more than it saves (-6 us/dispatch).
//  (r2-r5) intra-block pipelining at HIP source level: compiler re-serializes
//        (VGPR evidence); safe register ping-pong needs 4-deep slots = 96 KiB
//        = 1 block/CU -> excluded by the r10 law. Structural ceiling of this
//        design space: ~1583 cyc/block-phase (LDS 768 + MFMA 621 + sync,
//        partially overlapped cross-block).
template <typename OutT, int MODE>
__global__ __launch_bounds__(512) void gemmA(
    const bf16* __restrict__ A, int lda,
    const bf16* __restrict__ Bt, long bzs, int ldb,
    OutT* __restrict__ C, int ldc,
    const float* __restrict__ bias0, const float* __restrict__ bias1,
    const float* __restrict__ bias2, float alpha, int K) {
  __shared__ __align__(16) bf16 As[3][256 * 32];
  __shared__ __align__(16) bf16 Bs[3][128 * 32];
  const int tid = threadIdx.x;
  const int lane = tid & 63;
  const int w = tid >> 6;
  const int wm = w & 3;
  const int wn = w >> 2;
  const int quad = lane >> 4;
  const int l15 = lane & 15;
  const int fse = (quad ^ ((l15 >> 1) & 3)) << 3;

  const int gx = gridDim.x;
  const int pid = blockIdx.y * gx + blockIdx.x;
  const int gsz = 8 * gx;
  const int bym = (pid / gsz) * 8 + (pid % 8);
  const int bxm = (pid % gsz) / 8;
  const int row0 = bym * 256;
  const int col0 = bxm * 128;

  const bf16* Arow = A + (long)row0 * lda;
  const bf16* Bcol;
  int grp = 0;
  if (MODE == MODE_QKV) {
    grp = col0 >> 10;
    Bcol = Bt + (long)grp * ((long)D_ * D_) + (long)(col0 & (D_ - 1)) * ldb;
  } else if (MODE == MODE_PV || MODE == MODE_EXP) {
    Bcol = Bt + (long)(row0 >> 11) * bzs + (long)col0 * ldb;
  } else {
    Bcol = Bt + (long)col0 * ldb;
  }

  const int sr = tid >> 2;
  const int sc = ((tid & 3) ^ ((tid >> 3) & 3)) << 3;
  const bf16* gA = Arow + (long)sr * lda + sc;
  const bf16* gB = Bcol + (long)sr * ldb + sc;
  const int dstoff = (tid >> 6) << 9;
  const long a128 = (long)128 * lda;

#define STAGE(h, s)                                                    \
  {                                                                    \
    const int kc_ = (h) * 32;                                          \
    bf16* da_ = &As[0][0] + (s) * (256 * 32) + dstoff;                 \
    bf16* db_ = &Bs[0][0] + (s) * (128 * 32) + dstoff;                 \
    async_copy16(gA + kc_, da_);                                       \
    async_copy16(gA + kc_ + a128, da_ + 4096);                         \
    async_copy16(gB + kc_, db_);                                       \
  }

#define READF(Ra, Rb, s)                                                   \
  {                                                                        \
    const bf16* pa_ = &As[0][0] + (s) * (256 * 32);                        \
    const bf16* pb_ = &Bs[0][0] + (s) * (128 * 32);                        \
    _Pragma("unroll") for (int j = 0; j < 4; ++j) {                        \
      Ra[j] = *(const bf16x8*)&pa_[(wm * 64 + j * 16 + l15) * 32 + fse];   \
      Rb[j] = *(const bf16x8*)&pb_[(wn * 64 + j * 16 + l15) * 32 + fse];   \
    }                                                                      \
  }

#define MM(Ra, Rb)                                                         \
  __builtin_amdgcn_s_setprio(1);                                           \
  _Pragma("unroll") for (int mi = 0; mi < 4; ++mi)                         \
      _Pragma("unroll") for (int ni = 0; ni < 4; ++ni) acc[mi][ni] =       \
          __builtin_amdgcn_mfma_f32_16x16x32_bf16(Ra[mi], Rb[ni],          \
                                                  acc[mi][ni], 0, 0, 0);   \
  __builtin_amdgcn_s_setprio(0);

  f32x4 acc[4][4];
#pragma unroll
  for (int i = 0; i < 4; ++i)
#pragma unroll
    for (int j = 0; j < 4; ++j) acc[i][j] = (f32x4){0.f, 0.f, 0.f, 0.f};

  const int nh = (K >> 6) << 1;

  STAGE(0, 0);
  STAGE(1, 1);
  asm volatile("s_waitcnt vmcnt(3)" ::: "memory");
  __builtin_amdgcn_s_barrier();
  __builtin_amdgcn_sched_barrier(0);

  int s0 = 0;
  for (int h = 0; h < nh; ++h) {
    bf16x8 af[4], bf[4];
    READF(af, bf, s0);
    if (h + 2 < nh) {
      const int s2 = (s0 >= 1) ? (s0 - 1) : 2;
      STAGE(h + 2, s2);
    }
    MM(af, bf);
    if (h + 2 < nh)
      asm volatile("s_waitcnt vmcnt(3)" ::: "memory");
    else if (h + 1 < nh)
      asm volatile("s_waitcnt vmcnt(0)" ::: "memory");
    if (h + 1 < nh) {
      __builtin_amdgcn_s_barrier();
      __builtin_amdgcn_sched_barrier(0);
    }
    s0 = (s0 == 2) ? 0 : (s0 + 1);
  }

#undef STAGE
#undef READF
#undef MM

  const float* bias = (MODE == MODE_QKV)
                          ? (grp == 0 ? bias0 : grp == 1 ? bias1 : bias2)
                          : bias0;
  const long NX = (long)B_ * S_ * D_;
  OutT* Cb = (MODE == MODE_QKV) ? C + (long)grp * NX : C;
#pragma unroll
  for (int mi = 0; mi < 4; ++mi)
#pragma unroll
    for (int ni = 0; ni < 4; ++ni) {
      const int col = col0 + wn * 64 + ni * 16 + l15;
      const int ccol = (MODE == MODE_QKV) ? (col & (D_ - 1)) : col;
      const float bv = bias ? bias[ccol] : 0.0f;
#pragma unroll
      for (int r = 0; r < 4; ++r) {
        const int row = row0 + wm * 64 + mi * 16 + quad * 4 + r;
        const float val = acc[mi][ni][r] * alpha + bv;
        if (MODE == MODE_EXP) {
          Cb[(long)row * ldc + col] = (OutT)__expf(val);
        } else if (MODE == MODE_QKV) {
          Cb[(long)row * D_ + ccol] = (OutT)val;
        } else {
          Cb[(long)row * ldc + col] = (OutT)val;
        }
      }
    }
}

// grid (S, B): P[b,q,:] = E[b,q,:] * sum_m bit_m(q,:) / rowsum_m / M, bf16.
__global__ __launch_bounds__(256) void softmax_combine(
    const f16* __restrict__ E, const u8* __restrict__ pk, bf16* __restrict__ P) {
  const int q = blockIdx.x;
  const int b = blockIdx.y;
  const int tid = threadIdx.x;
  const int lane = tid & 63;
  const int wv = tid >> 6;
  __shared__ float4 red[4];

  float e[8];
  {
    const f16x8 h = *(const f16x8*)(E + ((long)b * S_ + q) * S_ + tid * 8);
#pragma unroll
    for (int j = 0; j < 8; ++j) e[j] = (float)h[j];
  }
  const unsigned long long mb =
      *(const unsigned long long*)(pk + (long)q * S_ + tid * 8);

  float4 s = {0.f, 0.f, 0.f, 0.f};
#pragma unroll
  for (int j = 0; j < 8; ++j) {
    const unsigned bits = (unsigned)(mb >> (8 * j)) & 0xF;
    const float ev = e[j];
    if (bits & 1) s.x += ev;
    if (bits & 2) s.y += ev;
    if (bits & 4) s.z += ev;
    if (bits & 8) s.w += ev;
  }
#pragma unroll
  for (int o = 32; o > 0; o >>= 1) {
    s.x += __shfl_xor(s.x, o, 64);
    s.y += __shfl_xor(s.y, o, 64);
    s.z += __shfl_xor(s.z, o, 64);
    s.w += __shfl_xor(s.w, o, 64);
  }
  if (lane == 0) red[wv] = s;
  __syncthreads();
  const float4 t0 = red[0], t1 = red[1], t2 = red[2], t3 = red[3];
  const float r0 = 0.25f / (t0.x + t1.x + t2.x + t3.x);
  const float r1 = 0.25f / (t0.y + t1.y + t2.y + t3.y);
  const float r2 = 0.25f / (t0.z + t1.z + t2.z + t3.z);
  const float r3 = 0.25f / (t0.w + t1.w + t2.w + t3.w);

  bf16x8 o;
#pragma unroll
  for (int j = 0; j < 8; ++j) {
    const unsigned bits = (unsigned)(mb >> (8 * j)) & 0xF;
    const float wgt = ((bits & 1) ? r0 : 0.f) + ((bits & 2) ? r1 : 0.f) +
                      ((bits & 4) ? r2 : 0.f) + ((bits & 8) ? r3 : 0.f);
    o[j] = (bf16)(e[j] * wgt);
  }
  *(bf16x8*)(P + ((long)b * S_ + q) * S_ + tid * 8) = o;
}

extern "C" void kernel_launch(void* const* d_in, const int* in_sizes, int n_in,
                              void* d_out, int out_size, void* d_ws, size_t ws_size,
                              hipStream_t stream) {
  const float* x = (const float*)d_in[0];
  const int* masks = (const int*)d_in[1];
  const float* bq = (const float*)d_in[3];
  const float* bk = (const float*)d_in[5];
  const float* bv = (const float*)d_in[7];
  const float* bo = (const float*)d_in[9];
  float* out = (float*)d_out;

  const long DD = (long)D_ * D_;
  const long SD = (long)S_ * D_;
  const long NX = (long)B_ * SD;
  const long SS = (long)S_ * S_;

  // ws: xc 16M | WT 8M | pk 4M | Q/K/V 48M | VT 16M | P 32M | E 32M = 156 MiB
  bf16* xc = (bf16*)d_ws;
  bf16* WqT = xc + NX;  // WkT, WvT, WoT contiguous after
  bf16* WoT = WqT + 3 * DD;
  u8* pk = (u8*)(WoT + DD);    // [S][S] mask bitfield
  bf16* Q = (bf16*)(pk + SS);  // K = Q+NX, V = K+NX (QKV epilogue relies on it)
  bf16* K = Q + NX;
  bf16* V = K + NX;
  bf16* VT = V + NX;
  bf16* P = VT + NX;                   // [B][S][S] bf16
  f16* E = (f16*)(P + (long)B_ * SS);  // [B][S][S] f16
  bf16* attn = Q;                      // attn overwrites dead Q

  dim3 blk(256);
  dim3 blk512(512);

  // fused prep: x->bf16, 4 weight transposes, mask pack (one launch)
  prep<<<dim3(7168), blk, 0, stream>>>(
      x, (const float*)d_in[2], (const float*)d_in[4], (const float*)d_in[6],
      (const float*)d_in[8], masks, xc, WqT, pk);

  // fused Q|K|V projection: [8192,1024] x [1024,3072]
  // grid 24x32 = 768 blocks = 1.5 rounds at 2 blocks/CU
  gemmA<bf16, MODE_QKV><<<dim3(24, 32), blk512, 0, stream>>>(
      xc, D_, WqT, 0, D_, Q, D_, bq, bk, bv, 1.0f, D_);

  // VT[b][d][s] = V[b][s][d]
  transposeB<<<dim3(16, 32, B_), blk, 0, stream>>>(V, VT, S_, D_, SD, SD);

  // E = exp(Q K^T / 32) : flat [8192,1024] x K[z][2048,1024], z = row>>11
  // grid 16x32 = 512 blocks = 1 exact round at 2 blocks/CU
  gemmA<f16, MODE_EXP><<<dim3(16, 32), blk512, 0, stream>>>(
      Q, D_, K, SD, D_, E, S_, nullptr, nullptr, nullptr, 1.0f / 32.0f, D_);

  // P = E * sum_m mask_m / rowsum_m / M
  softmax_combine<<<dim3(S_, B_), blk, 0, stream>>>(E, pk, P);

  // attn = P @ V : flat [8192,2048] x VT[z][1024,2048], K=2048
  // grid 8x32 = 256 blocks (spreads 1/CU)
  gemmA<bf16, MODE_PV><<<dim3(8, 32), blk512, 0, stream>>>(
      P, S_, VT, SD, S_, attn, D_, nullptr, nullptr, nullptr, 1.0f, S_);

  // out = attn @ Wo + bo : fp32 epilogue straight to d_out
  gemmA<float, MODE_PLAIN><<<dim3(8, 32), blk512, 0, stream>>>(
      attn, D_, WoT, 0, D_, out, D_, bo, nullptr, nullptr, 1.0f, D_);
}